// Round 13
// baseline (341.229 us; speedup 1.0000x reference)
//
#include <hip/hip_runtime.h>
#include <hip/hip_bf16.h>
#include <type_traits>

typedef __attribute__((ext_vector_type(8))) short bf16x8;
typedef __attribute__((ext_vector_type(8))) unsigned short u16x8;
typedef __attribute__((ext_vector_type(4))) float f32x4;

__device__ __forceinline__ unsigned short f2b(float f) {
  union { float f; unsigned u; } c; c.f = f;
  return (unsigned short)((c.u + 0x7fffu + ((c.u >> 16) & 1u)) >> 16);
}
__device__ __forceinline__ float b2f(unsigned short v) {
  return __uint_as_float((unsigned)v << 16);
}

// ---------------- GEMM body: C[M,128] = act(A[M,K] @ W (+bias)), C bf16 ----------------
// 1x4 waves of BMx32 (B slice per wave read direct from global — L2-resident WT).
// LARGE BKT: few serial K-steps, deep independent staging loads (Little's law: maximize
// bytes in flight per thread). Loads are issued ALL-FIRST, then written to LDS.
// LOGITS=1: emit a_src/a_dst[row][head] (head = wc).
template<int BM, int K, int BKT, int ACT, int LOGITS, typename AT>
__device__ __forceinline__ void gemm_body(
    int bid, unsigned short* As,
    const AT* __restrict__ A, int M,
    const unsigned short* __restrict__ WT, const float* __restrict__ bias,
    unsigned short* __restrict__ C,
    const float* __restrict__ att_src, const float* __restrict__ att_dst,
    float* __restrict__ a_src, float* __restrict__ a_dst)
{
  constexpr int LSW = BKT + 8;          // shorts per LDS row (pad -> conflict-free)
  constexpr int MF = BM / 16;
  constexpr int NF = 2;
  const int t = threadIdx.x;
  const int lane = t & 63;
  const int wc = t >> 6;
  const int fr = lane & 15;
  const int kb = lane >> 4;
  const long row0 = (long)bid * BM;

  f32x4 acc[MF][NF] = {};

  for (int k0 = 0; k0 < K; k0 += BKT) {
    if constexpr (std::is_same<AT, float>::value) {
      constexpr int NU = BM * (BKT / 4) / 256;    // float4 units per thread
      float4 rv[NU];
#pragma unroll
      for (int i = 0; i < NU; ++i) {              // issue ALL loads (independent)
        int idx = t + i * 256;
        int r = idx / (BKT / 4);
        int kq = idx % (BKT / 4);
        long gr = row0 + r; if (gr >= M) gr = M - 1;
        rv[i] = *(const float4*)(A + gr * K + k0 + kq * 4);
      }
#pragma unroll
      for (int i = 0; i < NU; ++i) {              // then convert+write
        int idx = t + i * 256;
        int r = idx / (BKT / 4);
        int kq = idx % (BKT / 4);
        ushort4 b;
        b.x = f2b(rv[i].x); b.y = f2b(rv[i].y); b.z = f2b(rv[i].z); b.w = f2b(rv[i].w);
        *(ushort4*)(&As[r * LSW + kq * 4]) = b;
      }
    } else {
      constexpr int NU = BM * (BKT / 8) / 256;    // u16x8 units per thread
      u16x8 rv[NU];
#pragma unroll
      for (int i = 0; i < NU; ++i) {
        int idx = t + i * 256;
        int r = idx / (BKT / 8);
        int k8 = idx % (BKT / 8);
        long gr = row0 + r; if (gr >= M) gr = M - 1;
        rv[i] = *(const u16x8*)(A + gr * K + k0 + k8 * 8);
      }
#pragma unroll
      for (int i = 0; i < NU; ++i) {
        int idx = t + i * 256;
        int r = idx / (BKT / 8);
        int k8 = idx % (BKT / 8);
        *(u16x8*)(&As[r * LSW + k8 * 8]) = rv[i];
      }
    }
    __syncthreads();
#pragma unroll
    for (int kk = 0; kk < BKT; kk += 32) {
      const int koff = kk + kb * 8;
      bf16x8 af[MF], bfr[NF];
#pragma unroll
      for (int n = 0; n < NF; ++n)
        bfr[n] = *(const bf16x8*)(WT + (long)(wc * 32 + n * 16 + fr) * K + k0 + koff);
#pragma unroll
      for (int m = 0; m < MF; ++m)
        af[m] = *(const bf16x8*)(&As[(m * 16 + fr) * LSW + koff]);
#pragma unroll
      for (int m = 0; m < MF; ++m)
#pragma unroll
        for (int n = 0; n < NF; ++n)
          acc[m][n] = __builtin_amdgcn_mfma_f32_16x16x32_bf16(af[m], bfr[n], acc[m][n], 0, 0, 0);
    }
    if (k0 + BKT < K) __syncthreads();   // readers done before next stage overwrites
  }

  float asv[NF], adv[NF];
  if (LOGITS) {
#pragma unroll
    for (int n = 0; n < NF; ++n) {
      int dim = n * 16 + fr;
      asv[n] = att_src[wc * 32 + dim];
      adv[n] = att_dst[wc * 32 + dim];
    }
  }

  // epilogue: C/D layout col=lane&15, row=(lane>>4)*4+reg
#pragma unroll
  for (int m = 0; m < MF; ++m) {
#pragma unroll
    for (int j = 0; j < 4; ++j) {
      long gr = row0 + m * 16 + kb * 4 + j;
      if (gr < M) {
#pragma unroll
        for (int n = 0; n < NF; ++n) {
          int c = wc * 32 + n * 16 + fr;
          float v = acc[m][n][j];
          if (bias) v += bias[c];
          if (ACT == 1) v = fmaxf(v, 0.f);
          C[gr * 128 + c] = f2b(v);
        }
      }
      if (LOGITS) {
        float sa = fmaf(acc[m][0][j], asv[0], acc[m][1][j] * asv[1]);
        float da = fmaf(acc[m][0][j], adv[0], acc[m][1][j] * adv[1]);
#pragma unroll
        for (int off = 1; off < 16; off <<= 1) {
          sa += __shfl_xor(sa, off);
          da += __shfl_xor(da, off);
        }
        if (fr == 0 && gr < M) {
          a_src[gr * 4 + wc] = sa;
          a_dst[gr * 4 + wc] = da;
        }
      }
    }
  }
}

// ---------------- CSR-build bodies ----------------
__device__ __forceinline__ void hist_body(int bid, int* cnt, const int* __restrict__ dst,
                                          int E, int* __restrict__ bcount, int nb)
{
  int t = threadIdx.x;
  for (int b = t; b < 512; b += 256) cnt[b] = 0;
  __syncthreads();
  int e0 = bid * 8192;
  for (int i = 0; i < 32; ++i) {
    int e = e0 + i * 256 + t;
    if (e < E) atomicAdd(&cnt[dst[e] >> 8], 1);
  }
  __syncthreads();
  for (int b = t; b < nb; b += 256) {
    int c = cnt[b];
    if (c > 0) atomicAdd(&bcount[b], c);
  }
}

__device__ __forceinline__ void scatter_body(int bid, int* s, const int* __restrict__ src,
                                             const int* __restrict__ dst, int E,
                                             int* __restrict__ bcur, int2* __restrict__ pairs)
{
  int* cnt = s;
  int* base = s + 512;
  int* rcur = s + 1024;
  int t = threadIdx.x;
  for (int b = t; b < 512; b += 256) { cnt[b] = 0; rcur[b] = 0; }
  __syncthreads();
  int e0 = bid * 8192;
  for (int i = 0; i < 32; ++i) {
    int e = e0 + i * 256 + t;
    if (e < E) atomicAdd(&cnt[dst[e] >> 8], 1);
  }
  __syncthreads();
  for (int b = t; b < 512; b += 256) {
    int c = cnt[b];
    if (c > 0) base[b] = atomicAdd(&bcur[b], c);
  }
  __syncthreads();
  for (int i = 0; i < 32; ++i) {
    int e = e0 + i * 256 + t;
    if (e < E) {
      int d = dst[e];
      int b = d >> 8;
      int off = atomicAdd(&rcur[b], 1);
      int2 p; p.x = src[e]; p.y = d;
      pairs[base[b] + off] = p;
    }
  }
}

// ---------------- merged launches ----------------
// mega1: tweets GEMM (BM=64,K=512,BKT=256) | news GEMM (BM=32,K=768,BKT=256) | hist
__global__ __launch_bounds__(256) void mega1_kernel(
    int nb_tw, int nb_news,
    const float* __restrict__ x_tw, int n_tw, const unsigned short* __restrict__ WT_tw,
    const float* __restrict__ b_tw, unsigned short* __restrict__ out_tw,
    const float* __restrict__ x_news, int n_news, const unsigned short* __restrict__ WT_news,
    const float* __restrict__ b_news, unsigned short* __restrict__ out_news,
    const int* __restrict__ dst, int E, int* __restrict__ bcount, int nb)
{
  __shared__ unsigned short sh[64 * (256 + 8)];   // 33.8 KB
  int bid = blockIdx.x;
  if (bid < nb_tw) {
    gemm_body<64, 512, 256, 1, 0, float>(bid, sh, x_tw, n_tw, WT_tw, b_tw, out_tw,
                                         nullptr, nullptr, nullptr, nullptr);
  } else if (bid < nb_tw + nb_news) {
    gemm_body<32, 768, 256, 1, 0, float>(bid - nb_tw, sh, x_news, n_news, WT_news,
                                         b_news, out_news, nullptr, nullptr, nullptr, nullptr);
  } else {
    hist_body(bid - nb_tw - nb_news, (int*)sh, dst, E, bcount, nb);
  }
}

// mega3: GAT1 GEMM+logits (BM=64,K=128,BKT=128 — single K-step) | bucket_scatter
__global__ __launch_bounds__(256) void mega3_kernel(
    int nb_gemm,
    const unsigned short* __restrict__ x_feat, int N, const unsigned short* __restrict__ WT_g1,
    unsigned short* __restrict__ h_feat,
    const float* __restrict__ g1as, const float* __restrict__ g1ad,
    float* __restrict__ a_src, float* __restrict__ a_dst,
    const int* __restrict__ src, const int* __restrict__ dst, int E,
    int* __restrict__ bcur, int2* __restrict__ pairs)
{
  __shared__ unsigned short sh[64 * (128 + 8)];   // 17.4 KB
  int bid = blockIdx.x;
  if (bid < nb_gemm) {
    gemm_body<64, 128, 128, 0, 1, unsigned short>(bid, sh, x_feat, N, WT_g1, nullptr,
                                                  h_feat, g1as, g1ad, a_src, a_dst);
  } else {
    scatter_body(bid - nb_gemm, (int*)sh, src, dst, E, bcur, pairs);
  }
}

template<int BM, int K, int BKT, int ACT, int LOGITS, typename AT>
__global__ __launch_bounds__(256) void gemm_kernel(
    const AT* __restrict__ A, int M,
    const unsigned short* __restrict__ WT, const float* __restrict__ bias,
    unsigned short* __restrict__ C,
    const float* __restrict__ att_src, const float* __restrict__ att_dst,
    float* __restrict__ a_src, float* __restrict__ a_dst)
{
  __shared__ unsigned short sh[BM * (BKT + 8)];
  gemm_body<BM, K, BKT, ACT, LOGITS, AT>(blockIdx.x, sh, A, M, WT, bias, C,
                                         att_src, att_dst, a_src, a_dst);
}

// ---------------- one-off weight transposes (all four fused) ----------------
__global__ void transpose_all_kernel(const float* __restrict__ W0, unsigned short* __restrict__ T0,
                                     const float* __restrict__ W1, unsigned short* __restrict__ T1,
                                     const float* __restrict__ W2, unsigned short* __restrict__ T2,
                                     const float* __restrict__ W3, unsigned short* __restrict__ T3)
{
  int r = blockIdx.x * 256 + threadIdx.x;
  if (r < 128 * 768) { int c = r / 768, k = r - c * 768; T0[r] = f2b(W0[(size_t)k * 128 + c]); return; }
  r -= 128 * 768;
  if (r < 128 * 512) { int c = r / 512, k = r - c * 512; T1[r] = f2b(W1[(size_t)k * 128 + c]); return; }
  r -= 128 * 512;
  if (r < 128 * 128) { T2[r] = f2b(W2[(size_t)(r & 127) * 128 + (r >> 7)]); return; }
  r -= 128 * 128;
  if (r < 128 * 128) { T3[r] = f2b(W3[(size_t)(r & 127) * 128 + (r >> 7)]); return; }
}

// ---------------- scan + per-bucket CSR finalize ----------------
__global__ __launch_bounds__(512) void bucket_scan_kernel(const int* __restrict__ bcount, int nb, int E,
                                                          int* __restrict__ bstart, int* __restrict__ bcur,
                                                          int* __restrict__ row_ptr, int N)
{
  __shared__ int s[512];
  int t = threadIdx.x;
  int my = (t < nb) ? bcount[t] : 0;
  s[t] = my;
  __syncthreads();
  for (int off = 1; off < 512; off <<= 1) {
    int v = (t >= off) ? s[t - off] : 0;
    __syncthreads();
    s[t] += v;
    __syncthreads();
  }
  int excl = s[t] - my;
  if (t < nb) { bstart[t] = excl; bcur[t] = excl; }
  if (t == 0) { bstart[nb] = E; row_ptr[N] = E; }
}

__global__ __launch_bounds__(256) void bucket_csr_kernel(const int2* __restrict__ pairs,
                                                         const int* __restrict__ bstart, int N,
                                                         int* __restrict__ row_ptr, int* __restrict__ col_idx)
{
  __shared__ int cnt[256];
  __shared__ int excl[256];
  __shared__ int cur[256];
  int t = threadIdx.x;
  int nodebase = blockIdx.x << 8;
  int start = bstart[blockIdx.x];
  int size = bstart[blockIdx.x + 1] - start;
  cnt[t] = 0;
  __syncthreads();
  for (int i = t; i < size; i += 256)
    atomicAdd(&cnt[pairs[start + i].y & 255], 1);
  __syncthreads();
  int my = cnt[t];
  excl[t] = my;
  __syncthreads();
  for (int off = 1; off < 256; off <<= 1) {
    int v = (t >= off) ? excl[t - off] : 0;
    __syncthreads();
    excl[t] += v;
    __syncthreads();
  }
  int ex = excl[t] - my;
  if (nodebase + t < N) row_ptr[nodebase + t] = start + ex;
  excl[t] = ex;
  cur[t] = 0;
  __syncthreads();
  for (int i = t; i < size; i += 256) {
    int2 p = pairs[start + i];
    int local = p.y & 255;
    int pos = start + excl[local] + atomicAdd(&cur[local], 1);
    col_idx[pos] = p.x;
  }
}

// ---------------- fused GAT aggregation (bf16 h): 4 edges per wave ----------------
__global__ void gat_aggregate_kernel(const unsigned short* __restrict__ h, const float* __restrict__ a_src,
                                     const float* __restrict__ a_dst, const int* __restrict__ row_ptr,
                                     const int* __restrict__ col_idx, const float* __restrict__ bias,
                                     int Nproc, unsigned short* __restrict__ out)
{
  int n = (blockIdx.x * blockDim.x + threadIdx.x) >> 6;
  int lane = threadIdx.x & 63;
  if (n >= Nproc) return;
  const int sub = lane >> 4;
  const int sl = lane & 15;
  const int head = sl >> 2;
  const int beg = row_ptr[n], end = row_ptr[n + 1];
  const float adst = a_dst[(size_t)n * 4 + head];

  float slf = a_src[(size_t)n * 4 + head] + adst;
  slf = fmaxf(slf, 0.2f * slf);
  float ps = (sub == 0) ? __expf(slf) : 0.f;
  float denom = ps;
  float acc[8];
  {
    const u16x8 hs = *(const u16x8*)(h + (size_t)n * 128 + 8 * sl);
#pragma unroll
    for (int j = 0; j < 8; ++j) acc[j] = ps * b2f(hs[j]);
  }

  int e = beg + sub;
  for (; e + 4 < end; e += 8) {
    const int s0 = col_idx[e];
    const int s1 = col_idx[e + 4];
    const u16x8 h0 = *(const u16x8*)(h + (size_t)s0 * 128 + 8 * sl);
    const u16x8 h1 = *(const u16x8*)(h + (size_t)s1 * 128 + 8 * sl);
    float l0 = a_src[(size_t)s0 * 4 + head] + adst;
    float l1 = a_src[(size_t)s1 * 4 + head] + adst;
    l0 = fmaxf(l0, 0.2f * l0);
    l1 = fmaxf(l1, 0.2f * l1);
    const float p0 = __expf(l0);
    const float p1 = __expf(l1);
    denom += p0 + p1;
#pragma unroll
    for (int j = 0; j < 8; ++j) {
      acc[j] = fmaf(p0, b2f(h0[j]), acc[j]);
      acc[j] = fmaf(p1, b2f(h1[j]), acc[j]);
    }
  }
  if (e < end) {
    const int s = col_idx[e];
    const u16x8 hv = *(const u16x8*)(h + (size_t)s * 128 + 8 * sl);
    float lg = a_src[(size_t)s * 4 + head] + adst;
    lg = fmaxf(lg, 0.2f * lg);
    const float p = __expf(lg);
    denom += p;
#pragma unroll
    for (int j = 0; j < 8; ++j) acc[j] = fmaf(p, b2f(hv[j]), acc[j]);
  }

#pragma unroll
  for (int j = 0; j < 8; ++j) {
    acc[j] += __shfl_xor(acc[j], 16);
    acc[j] += __shfl_xor(acc[j], 32);
  }
  denom += __shfl_xor(denom, 16);
  denom += __shfl_xor(denom, 32);

  if (sub == 0) {
    const float inv = 1.0f / (denom + 1e-16f);
    const float4 b0 = *(const float4*)(bias + 8 * sl);
    const float4 b1 = *(const float4*)(bias + 8 * sl + 4);
    float o[8];
    o[0] = acc[0] * inv + b0.x; o[1] = acc[1] * inv + b0.y;
    o[2] = acc[2] * inv + b0.z; o[3] = acc[3] * inv + b0.w;
    o[4] = acc[4] * inv + b1.x; o[5] = acc[5] * inv + b1.y;
    o[6] = acc[6] * inv + b1.z; o[7] = acc[7] * inv + b1.w;
    u16x8 r;
#pragma unroll
    for (int j = 0; j < 8; ++j) {
      float v = (o[j] > 0.f) ? o[j] : expm1f(o[j]);
      r[j] = f2b(v);
    }
    *(u16x8*)(out + (size_t)n * 128 + 8 * sl) = r;
  }
}

// ---------------- layer-2 aggregation FUSED with classifier (news rows only) ----------------
// Same gather phase; then all 64 lanes hold the full fp32 output row (after butterfly),
// and the wave computes relu(x@Wc1+bc1)@Wc2+bc2 in-register (no x_feat round-trip).
__global__ void gat_agg_cls_kernel(const unsigned short* __restrict__ h, const float* __restrict__ a_src,
                                   const float* __restrict__ a_dst, const int* __restrict__ row_ptr,
                                   const int* __restrict__ col_idx, const float* __restrict__ bias,
                                   int n_news,
                                   const float* __restrict__ Wc1, const float* __restrict__ bc1,
                                   const float* __restrict__ Wc2, const float* __restrict__ bc2,
                                   float* __restrict__ out)
{
  int n = (blockIdx.x * blockDim.x + threadIdx.x) >> 6;
  int lane = threadIdx.x & 63;
  if (n >= n_news) return;
  const int sub = lane >> 4;
  const int sl = lane & 15;
  const int head = sl >> 2;
  const int beg = row_ptr[n], end = row_ptr[n + 1];
  const float adst = a_dst[(size_t)n * 4 + head];

  float slf = a_src[(size_t)n * 4 + head] + adst;
  slf = fmaxf(slf, 0.2f * slf);
  float ps = (sub == 0) ? __expf(slf) : 0.f;
  float denom = ps;
  float acc[8];
  {
    const u16x8 hs = *(const u16x8*)(h + (size_t)n * 128 + 8 * sl);
#pragma unroll
    for (int j = 0; j < 8; ++j) acc[j] = ps * b2f(hs[j]);
  }

  int e = beg + sub;
  for (; e + 4 < end; e += 8) {
    const int s0 = col_idx[e];
    const int s1 = col_idx[e + 4];
    const u16x8 h0 = *(const u16x8*)(h + (size_t)s0 * 128 + 8 * sl);
    const u16x8 h1 = *(const u16x8*)(h + (size_t)s1 * 128 + 8 * sl);
    float l0 = a_src[(size_t)s0 * 4 + head] + adst;
    float l1 = a_src[(size_t)s1 * 4 + head] + adst;
    l0 = fmaxf(l0, 0.2f * l0);
    l1 = fmaxf(l1, 0.2f * l1);
    const float p0 = __expf(l0);
    const float p1 = __expf(l1);
    denom += p0 + p1;
#pragma unroll
    for (int j = 0; j < 8; ++j) {
      acc[j] = fmaf(p0, b2f(h0[j]), acc[j]);
      acc[j] = fmaf(p1, b2f(h1[j]), acc[j]);
    }
  }
  if (e < end) {
    const int s = col_idx[e];
    const u16x8 hv = *(const u16x8*)(h + (size_t)s * 128 + 8 * sl);
    float lg = a_src[(size_t)s * 4 + head] + adst;
    lg = fmaxf(lg, 0.2f * lg);
    const float p = __expf(lg);
    denom += p;
#pragma unroll
    for (int j = 0; j < 8; ++j) acc[j] = fmaf(p, b2f(hv[j]), acc[j]);
  }

#pragma unroll
  for (int j = 0; j < 8; ++j) {
    acc[j] += __shfl_xor(acc[j], 16);
    acc[j] += __shfl_xor(acc[j], 32);
  }
  denom += __shfl_xor(denom, 16);
  denom += __shfl_xor(denom, 32);

  // full fp32 node row on every lane (lane sl holds dims 8*sl..8*sl+7)
  const float inv = 1.0f / (denom + 1e-16f);
  const float4 b0 = *(const float4*)(bias + 8 * sl);
  const float4 b1 = *(const float4*)(bias + 8 * sl + 4);
  float o[8];
  o[0] = acc[0] * inv + b0.x; o[1] = acc[1] * inv + b0.y;
  o[2] = acc[2] * inv + b0.z; o[3] = acc[3] * inv + b0.w;
  o[4] = acc[4] * inv + b1.x; o[5] = acc[5] * inv + b1.y;
  o[6] = acc[6] * inv + b1.z; o[7] = acc[7] * inv + b1.w;
#pragma unroll
  for (int j = 0; j < 8; ++j)
    o[j] = (o[j] > 0.f) ? o[j] : expm1f(o[j]);    // ELU

  // classifier: lane owns column `lane` of the 64-wide hidden layer
  float c = 0.f;
#pragma unroll
  for (int j = 0; j < 8; ++j) {
#pragma unroll
    for (int kb = 0; kb < 16; ++kb) {
      float x = __shfl(o[j], kb);                 // dim = kb*8 + j (from lane kb, sub 0)
      c = fmaf(x, Wc1[(kb * 8 + j) * 64 + lane], c);
    }
  }
  c += bc1[lane];
  c = fmaxf(c, 0.f);
  float o0 = c * Wc2[lane * 2 + 0];
  float o1 = c * Wc2[lane * 2 + 1];
#pragma unroll
  for (int off = 1; off < 64; off <<= 1) {
    o0 += __shfl_xor(o0, off);
    o1 += __shfl_xor(o1, off);
  }
  if (lane == 0) {
    out[(size_t)n * 2 + 0] = o0 + bc2[0];
    out[(size_t)n * 2 + 1] = o1 + bc2[1];
  }
}

extern "C" void kernel_launch(void* const* d_in, const int* in_sizes, int n_in,
                              void* d_out, int out_size, void* d_ws, size_t ws_size,
                              hipStream_t stream)
{
  const float* x_news = (const float*)d_in[0];
  const float* x_tw   = (const float*)d_in[1];
  const int*   ei     = (const int*)d_in[2];
  const float* W_news = (const float*)d_in[3];
  const float* b_news = (const float*)d_in[4];
  const float* W_tw   = (const float*)d_in[5];
  const float* b_tw   = (const float*)d_in[6];
  const float* g1W  = (const float*)d_in[7];
  const float* g1as = (const float*)d_in[8];
  const float* g1ad = (const float*)d_in[9];
  const float* g1b  = (const float*)d_in[10];
  const float* g2W  = (const float*)d_in[11];
  const float* g2as = (const float*)d_in[12];
  const float* g2ad = (const float*)d_in[13];
  const float* g2b  = (const float*)d_in[14];
  const float* Wc1  = (const float*)d_in[15];
  const float* bc1  = (const float*)d_in[16];
  const float* Wc2  = (const float*)d_in[17];
  const float* bc2  = (const float*)d_in[18];

  const int n_news = in_sizes[0] / 768;
  const int n_tw   = in_sizes[1] / 512;
  const int N = n_news + n_tw;
  const int E = in_sizes[2] / 2;
  const int* src = ei;
  const int* dst = ei + E;
  const int nb = (N + 255) >> 8;      // buckets of 256 nodes

  char* ws = (char*)d_ws;
  size_t off = 0;
  auto alloc = [&](size_t bytes) -> void* {
    void* p = ws + off;
    off += (bytes + 255) & ~(size_t)255;
    return p;
  };
  unsigned short* x_feat = (unsigned short*)alloc((size_t)N * 128 * 2);
  unsigned short* h_feat = (unsigned short*)alloc((size_t)N * 128 * 2);
  float* a_src   = (float*)alloc((size_t)N * 4 * 4);
  float* a_dst   = (float*)alloc((size_t)N * 4 * 4);
  int*   row_ptr = (int*)alloc((size_t)(N + 1) * 4);
  int*   col_idx = (int*)alloc((size_t)E * 4);
  int2*  pairs   = (int2*)alloc((size_t)E * 8);
  int*   bcount  = (int*)alloc(2048);
  int*   bstart  = (int*)alloc(2052);
  int*   bcur    = (int*)alloc(2048);
  unsigned short* WT_news = (unsigned short*)alloc((size_t)128 * 768 * 2);
  unsigned short* WT_tw   = (unsigned short*)alloc((size_t)128 * 512 * 2);
  unsigned short* WT_g1   = (unsigned short*)alloc((size_t)128 * 128 * 2);
  unsigned short* WT_g2   = (unsigned short*)alloc((size_t)128 * 128 * 2);

  hipMemsetAsync(bcount, 0, 2048, stream);

  // one-off weight transposes (fp32 -> bf16, [K][128] -> [128][K]) — single launch
  transpose_all_kernel<<<768, 256, 0, stream>>>(W_news, WT_news, W_tw, WT_tw, g1W, WT_g1, g2W, WT_g2);

  // mega1: tweets GEMM | news GEMM | bucket histogram (all independent)
  const int nb_tw = (n_tw + 63) / 64;
  const int nb_news = (n_news + 31) / 32;
  const int nb_hist = (E + 8191) / 8192;
  mega1_kernel<<<nb_tw + nb_news + nb_hist, 256, 0, stream>>>(
      nb_tw, nb_news,
      x_tw, n_tw, WT_tw, b_tw, x_feat + (size_t)n_news * 128,
      x_news, n_news, WT_news, b_news, x_feat,
      dst, E, bcount, nb);

  // bucket scan (tiny)
  bucket_scan_kernel<<<1, 512, 0, stream>>>(bcount, nb, E, bstart, bcur, row_ptr, N);

  // mega3: GAT1 GEMM+logits | bucket scatter (both ready after scan)
  const int nb_g = (N + 63) / 64;
  mega3_kernel<<<nb_g + nb_hist, 256, 0, stream>>>(
      nb_g, x_feat, N, WT_g1, h_feat, g1as, g1ad, a_src, a_dst,
      src, dst, E, bcur, pairs);

  // per-bucket CSR finalize
  bucket_csr_kernel<<<nb, 256, 0, stream>>>(pairs, bstart, N, row_ptr, col_idx);

  // GAT layer 1 aggregation (full N: outputs feed layer-2 GEMM as gathered srcs)
  gat_aggregate_kernel<<<(N + 3) / 4, 256, 0, stream>>>(h_feat, a_src, a_dst, row_ptr, col_idx, g1b, N, x_feat);

  // GAT layer 2: GEMM (full N) + aggregation fused with classifier (news rows only)
  gemm_kernel<64, 128, 128, 0, 1, unsigned short><<<nb_g, 256, 0, stream>>>(
      x_feat, N, WT_g2, nullptr, h_feat, g2as, g2ad, a_src, a_dst);
  gat_agg_cls_kernel<<<(n_news + 3) / 4, 256, 0, stream>>>(
      h_feat, a_src, a_dst, row_ptr, col_idx, g2b, n_news,
      Wc1, bc1, Wc2, bc2, (float*)d_out);
}

// Round 14
// 307.519 us; speedup vs baseline: 1.1096x; 1.1096x over previous
//
#include <hip/hip_runtime.h>
#include <hip/hip_bf16.h>
#include <type_traits>

typedef __attribute__((ext_vector_type(8))) short bf16x8;
typedef __attribute__((ext_vector_type(8))) unsigned short u16x8;
typedef __attribute__((ext_vector_type(4))) float f32x4;

__device__ __forceinline__ unsigned short f2b(float f) {
  union { float f; unsigned u; } c; c.f = f;
  return (unsigned short)((c.u + 0x7fffu + ((c.u >> 16) & 1u)) >> 16);
}
__device__ __forceinline__ float b2f(unsigned short v) {
  return __uint_as_float((unsigned)v << 16);
}

constexpr int BK = 64;
constexpr int LS = BK + 8;   // 72 shorts = 144B row stride (pad kills LDS conflicts)

// ---------------- GEMM body: C[M,128] = act(A[M,K] @ W (+bias)), C bf16 ----------------
// R12 known-best structure: LDS staging of A and B, BK=64, 2 barriers per K-step.
// BM<=64 -> 1x4 waves of BMx32. LOGITS=1: emit a_src/a_dst[row][head] (head = wc).
template<int BM, int K, int ACT, int LOGITS, typename AT>
__device__ __forceinline__ void gemm_body(
    int bid, unsigned short* As, unsigned short* Bs,
    const AT* __restrict__ A, int M,
    const unsigned short* __restrict__ WT, const float* __restrict__ bias,
    unsigned short* __restrict__ C,
    const float* __restrict__ att_src, const float* __restrict__ att_dst,
    float* __restrict__ a_src, float* __restrict__ a_dst)
{
  constexpr int WTN = 32;        // private col slice per wave
  constexpr int MF = BM / 16;
  constexpr int NF = 2;
  const int t = threadIdx.x;
  const int lane = t & 63;
  const int wc = t >> 6;
  const long row0 = (long)bid * BM;

  f32x4 acc[MF][NF] = {};

  for (int k0 = 0; k0 < K; k0 += BK) {
    if constexpr (std::is_same<AT, float>::value) {
      // stage A: BMx64 fp32 -> bf16 (coalesced float4 reads)
#pragma unroll
      for (int i = 0; i < BM / 16; ++i) {
        int idx = t + i * 256;
        int r = idx >> 4;
        int kq = idx & 15;
        long gr = row0 + r; if (gr >= M) gr = M - 1;
        const float4 v = *(const float4*)(A + gr * K + k0 + kq * 4);
        ushort4 b;
        b.x = f2b(v.x); b.y = f2b(v.y); b.z = f2b(v.z); b.w = f2b(v.w);
        *(ushort4*)(&As[r * LS + kq * 4]) = b;
      }
    } else {
      // stage A: BMx64 bf16 passthrough (16B loads)
#pragma unroll
      for (int i = 0; i < BM / 32; ++i) {
        int idx = t + i * 256;
        int r = idx >> 3;
        int k8 = idx & 7;
        long gr = row0 + r; if (gr >= M) gr = M - 1;
        u16x8 v = *(const u16x8*)(A + gr * K + k0 + k8 * 8);
        *(u16x8*)(&As[r * LS + k8 * 8]) = v;
      }
    }
    // stage B: WT[col][k] bf16 passthrough (16B coalesced loads)
#pragma unroll
    for (int i = 0; i < 4; ++i) {
      int idx = t + i * 256;
      int col = idx >> 3;
      int k8 = idx & 7;
      u16x8 v = *(const u16x8*)(WT + (long)col * K + k0 + k8 * 8);
      *(u16x8*)(&Bs[col * LS + k8 * 8]) = v;
    }
    __syncthreads();
#pragma unroll
    for (int kk = 0; kk < BK; kk += 32) {
      const int koff = kk + (lane >> 4) * 8;
      bf16x8 af[MF], bfr[NF];
#pragma unroll
      for (int n = 0; n < NF; ++n)
        bfr[n] = *(const bf16x8*)(&Bs[(wc * WTN + n * 16 + (lane & 15)) * LS + koff]);
#pragma unroll
      for (int m = 0; m < MF; ++m)
        af[m] = *(const bf16x8*)(&As[(m * 16 + (lane & 15)) * LS + koff]);
#pragma unroll
      for (int m = 0; m < MF; ++m)
#pragma unroll
        for (int n = 0; n < NF; ++n)
          acc[m][n] = __builtin_amdgcn_mfma_f32_16x16x32_bf16(af[m], bfr[n], acc[m][n], 0, 0, 0);
    }
    __syncthreads();
  }

  float asv[NF], adv[NF];
  if (LOGITS) {
#pragma unroll
    for (int n = 0; n < NF; ++n) {
      int dim = n * 16 + (lane & 15);
      asv[n] = att_src[wc * 32 + dim];
      adv[n] = att_dst[wc * 32 + dim];
    }
  }

  // epilogue: C/D layout col=lane&15, row=(lane>>4)*4+reg
#pragma unroll
  for (int m = 0; m < MF; ++m) {
#pragma unroll
    for (int j = 0; j < 4; ++j) {
      long gr = row0 + m * 16 + (lane >> 4) * 4 + j;
      if (gr < M) {
#pragma unroll
        for (int n = 0; n < NF; ++n) {
          int c = wc * WTN + n * 16 + (lane & 15);
          float v = acc[m][n][j];
          if (bias) v += bias[c];
          if (ACT == 1) v = fmaxf(v, 0.f);
          C[gr * 128 + c] = f2b(v);
        }
      }
      if (LOGITS) {
        float sa = fmaf(acc[m][0][j], asv[0], acc[m][1][j] * asv[1]);
        float da = fmaf(acc[m][0][j], adv[0], acc[m][1][j] * adv[1]);
#pragma unroll
        for (int off = 1; off < 16; off <<= 1) {
          sa += __shfl_xor(sa, off);
          da += __shfl_xor(da, off);
        }
        if ((lane & 15) == 0 && gr < M) {
          a_src[gr * 4 + wc] = sa;
          a_dst[gr * 4 + wc] = da;
        }
      }
    }
  }
}

// ---------------- CSR-build bodies ----------------
__device__ __forceinline__ void hist_body(int bid, int* cnt, const int* __restrict__ dst,
                                          int E, int* __restrict__ bcount, int nb)
{
  int t = threadIdx.x;
  for (int b = t; b < 512; b += 256) cnt[b] = 0;
  __syncthreads();
  int e0 = bid * 8192;
  for (int i = 0; i < 32; ++i) {
    int e = e0 + i * 256 + t;
    if (e < E) atomicAdd(&cnt[dst[e] >> 8], 1);
  }
  __syncthreads();
  for (int b = t; b < nb; b += 256) {
    int c = cnt[b];
    if (c > 0) atomicAdd(&bcount[b], c);
  }
}

__device__ __forceinline__ void scatter_body(int bid, int* s, const int* __restrict__ src,
                                             const int* __restrict__ dst, int E,
                                             int* __restrict__ bcur, int2* __restrict__ pairs)
{
  int* cnt = s;
  int* base = s + 512;
  int* rcur = s + 1024;
  int t = threadIdx.x;
  for (int b = t; b < 512; b += 256) { cnt[b] = 0; rcur[b] = 0; }
  __syncthreads();
  int e0 = bid * 8192;
  for (int i = 0; i < 32; ++i) {
    int e = e0 + i * 256 + t;
    if (e < E) atomicAdd(&cnt[dst[e] >> 8], 1);
  }
  __syncthreads();
  for (int b = t; b < 512; b += 256) {
    int c = cnt[b];
    if (c > 0) base[b] = atomicAdd(&bcur[b], c);
  }
  __syncthreads();
  for (int i = 0; i < 32; ++i) {
    int e = e0 + i * 256 + t;
    if (e < E) {
      int d = dst[e];
      int b = d >> 8;
      int off = atomicAdd(&rcur[b], 1);
      int2 p; p.x = src[e]; p.y = d;
      pairs[base[b] + off] = p;
    }
  }
}

// ---------------- merged launches ----------------
__global__ __launch_bounds__(256) void mega1_kernel(
    int nb_tw, int nb_news,
    const float* __restrict__ x_tw, int n_tw, const unsigned short* __restrict__ WT_tw,
    const float* __restrict__ b_tw, unsigned short* __restrict__ out_tw,
    const float* __restrict__ x_news, int n_news, const unsigned short* __restrict__ WT_news,
    const float* __restrict__ b_news, unsigned short* __restrict__ out_news,
    const int* __restrict__ dst, int E, int* __restrict__ bcount, int nb)
{
  __shared__ unsigned short sh[(64 + 128) * LS];
  int bid = blockIdx.x;
  if (bid < nb_tw) {
    gemm_body<64, 512, 1, 0, float>(bid, sh, sh + 64 * LS, x_tw, n_tw, WT_tw, b_tw, out_tw,
                                    nullptr, nullptr, nullptr, nullptr);
  } else if (bid < nb_tw + nb_news) {
    gemm_body<32, 768, 1, 0, float>(bid - nb_tw, sh, sh + 32 * LS, x_news, n_news, WT_news,
                                    b_news, out_news, nullptr, nullptr, nullptr, nullptr);
  } else {
    hist_body(bid - nb_tw - nb_news, (int*)sh, dst, E, bcount, nb);
  }
}

__global__ __launch_bounds__(256) void mega3_kernel(
    int nb_gemm,
    const unsigned short* __restrict__ x_feat, int N, const unsigned short* __restrict__ WT_g1,
    unsigned short* __restrict__ h_feat,
    const float* __restrict__ g1as, const float* __restrict__ g1ad,
    float* __restrict__ a_src, float* __restrict__ a_dst,
    const int* __restrict__ src, const int* __restrict__ dst, int E,
    int* __restrict__ bcur, int2* __restrict__ pairs)
{
  __shared__ unsigned short sh[(64 + 128) * LS];
  int bid = blockIdx.x;
  if (bid < nb_gemm) {
    gemm_body<64, 128, 0, 1, unsigned short>(bid, sh, sh + 64 * LS, x_feat, N, WT_g1, nullptr,
                                             h_feat, g1as, g1ad, a_src, a_dst);
  } else {
    scatter_body(bid - nb_gemm, (int*)sh, src, dst, E, bcur, pairs);
  }
}

template<int BM, int K, int ACT, int LOGITS, typename AT>
__global__ __launch_bounds__(256) void gemm_kernel(
    const AT* __restrict__ A, int M,
    const unsigned short* __restrict__ WT, const float* __restrict__ bias,
    unsigned short* __restrict__ C,
    const float* __restrict__ att_src, const float* __restrict__ att_dst,
    float* __restrict__ a_src, float* __restrict__ a_dst)
{
  __shared__ unsigned short sh[(BM + 128) * LS];
  gemm_body<BM, K, ACT, LOGITS, AT>(blockIdx.x, sh, sh + BM * LS, A, M, WT, bias, C,
                                    att_src, att_dst, a_src, a_dst);
}

// ---------------- one-off weight transposes (all four fused) ----------------
__global__ void transpose_all_kernel(const float* __restrict__ W0, unsigned short* __restrict__ T0,
                                     const float* __restrict__ W1, unsigned short* __restrict__ T1,
                                     const float* __restrict__ W2, unsigned short* __restrict__ T2,
                                     const float* __restrict__ W3, unsigned short* __restrict__ T3)
{
  int r = blockIdx.x * 256 + threadIdx.x;
  if (r < 128 * 768) { int c = r / 768, k = r - c * 768; T0[r] = f2b(W0[(size_t)k * 128 + c]); return; }
  r -= 128 * 768;
  if (r < 128 * 512) { int c = r / 512, k = r - c * 512; T1[r] = f2b(W1[(size_t)k * 128 + c]); return; }
  r -= 128 * 512;
  if (r < 128 * 128) { T2[r] = f2b(W2[(size_t)(r & 127) * 128 + (r >> 7)]); return; }
  r -= 128 * 128;
  if (r < 128 * 128) { T3[r] = f2b(W3[(size_t)(r & 127) * 128 + (r >> 7)]); return; }
}

// ---------------- scan + per-bucket CSR finalize ----------------
__global__ __launch_bounds__(512) void bucket_scan_kernel(const int* __restrict__ bcount, int nb, int E,
                                                          int* __restrict__ bstart, int* __restrict__ bcur,
                                                          int* __restrict__ row_ptr, int N)
{
  __shared__ int s[512];
  int t = threadIdx.x;
  int my = (t < nb) ? bcount[t] : 0;
  s[t] = my;
  __syncthreads();
  for (int off = 1; off < 512; off <<= 1) {
    int v = (t >= off) ? s[t - off] : 0;
    __syncthreads();
    s[t] += v;
    __syncthreads();
  }
  int excl = s[t] - my;
  if (t < nb) { bstart[t] = excl; bcur[t] = excl; }
  if (t == 0) { bstart[nb] = E; row_ptr[N] = E; }
}

__global__ __launch_bounds__(256) void bucket_csr_kernel(const int2* __restrict__ pairs,
                                                         const int* __restrict__ bstart, int N,
                                                         int* __restrict__ row_ptr, int* __restrict__ col_idx)
{
  __shared__ int cnt[256];
  __shared__ int excl[256];
  __shared__ int cur[256];
  int t = threadIdx.x;
  int nodebase = blockIdx.x << 8;
  int start = bstart[blockIdx.x];
  int size = bstart[blockIdx.x + 1] - start;
  cnt[t] = 0;
  __syncthreads();
  for (int i = t; i < size; i += 256)
    atomicAdd(&cnt[pairs[start + i].y & 255], 1);
  __syncthreads();
  int my = cnt[t];
  excl[t] = my;
  __syncthreads();
  for (int off = 1; off < 256; off <<= 1) {
    int v = (t >= off) ? excl[t - off] : 0;
    __syncthreads();
    excl[t] += v;
    __syncthreads();
  }
  int ex = excl[t] - my;
  if (nodebase + t < N) row_ptr[nodebase + t] = start + ex;
  excl[t] = ex;
  cur[t] = 0;
  __syncthreads();
  for (int i = t; i < size; i += 256) {
    int2 p = pairs[start + i];
    int local = p.y & 255;
    int pos = start + excl[local] + atomicAdd(&cur[local], 1);
    col_idx[pos] = p.x;
  }
}

// ---------------- fused GAT aggregation (bf16 h): 4 edges per wave ----------------
__global__ void gat_aggregate_kernel(const unsigned short* __restrict__ h, const float* __restrict__ a_src,
                                     const float* __restrict__ a_dst, const int* __restrict__ row_ptr,
                                     const int* __restrict__ col_idx, const float* __restrict__ bias,
                                     int Nproc, unsigned short* __restrict__ out)
{
  int n = (blockIdx.x * blockDim.x + threadIdx.x) >> 6;
  int lane = threadIdx.x & 63;
  if (n >= Nproc) return;
  const int sub = lane >> 4;
  const int sl = lane & 15;
  const int head = sl >> 2;
  const int beg = row_ptr[n], end = row_ptr[n + 1];
  const float adst = a_dst[(size_t)n * 4 + head];

  float slf = a_src[(size_t)n * 4 + head] + adst;
  slf = fmaxf(slf, 0.2f * slf);
  float ps = (sub == 0) ? __expf(slf) : 0.f;
  float denom = ps;
  float acc[8];
  {
    const u16x8 hs = *(const u16x8*)(h + (size_t)n * 128 + 8 * sl);
#pragma unroll
    for (int j = 0; j < 8; ++j) acc[j] = ps * b2f(hs[j]);
  }

  int e = beg + sub;
  for (; e + 4 < end; e += 8) {
    const int s0 = col_idx[e];
    const int s1 = col_idx[e + 4];
    const u16x8 h0 = *(const u16x8*)(h + (size_t)s0 * 128 + 8 * sl);
    const u16x8 h1 = *(const u16x8*)(h + (size_t)s1 * 128 + 8 * sl);
    float l0 = a_src[(size_t)s0 * 4 + head] + adst;
    float l1 = a_src[(size_t)s1 * 4 + head] + adst;
    l0 = fmaxf(l0, 0.2f * l0);
    l1 = fmaxf(l1, 0.2f * l1);
    const float p0 = __expf(l0);
    const float p1 = __expf(l1);
    denom += p0 + p1;
#pragma unroll
    for (int j = 0; j < 8; ++j) {
      acc[j] = fmaf(p0, b2f(h0[j]), acc[j]);
      acc[j] = fmaf(p1, b2f(h1[j]), acc[j]);
    }
  }
  if (e < end) {
    const int s = col_idx[e];
    const u16x8 hv = *(const u16x8*)(h + (size_t)s * 128 + 8 * sl);
    float lg = a_src[(size_t)s * 4 + head] + adst;
    lg = fmaxf(lg, 0.2f * lg);
    const float p = __expf(lg);
    denom += p;
#pragma unroll
    for (int j = 0; j < 8; ++j) acc[j] = fmaf(p, b2f(hv[j]), acc[j]);
  }

#pragma unroll
  for (int j = 0; j < 8; ++j) {
    acc[j] += __shfl_xor(acc[j], 16);
    acc[j] += __shfl_xor(acc[j], 32);
  }
  denom += __shfl_xor(denom, 16);
  denom += __shfl_xor(denom, 32);

  if (sub == 0) {
    const float inv = 1.0f / (denom + 1e-16f);
    const float4 b0 = *(const float4*)(bias + 8 * sl);
    const float4 b1 = *(const float4*)(bias + 8 * sl + 4);
    float o[8];
    o[0] = acc[0] * inv + b0.x; o[1] = acc[1] * inv + b0.y;
    o[2] = acc[2] * inv + b0.z; o[3] = acc[3] * inv + b0.w;
    o[4] = acc[4] * inv + b1.x; o[5] = acc[5] * inv + b1.y;
    o[6] = acc[6] * inv + b1.z; o[7] = acc[7] * inv + b1.w;
    u16x8 r;
#pragma unroll
    for (int j = 0; j < 8; ++j) {
      float v = (o[j] > 0.f) ? o[j] : expm1f(o[j]);
      r[j] = f2b(v);
    }
    *(u16x8*)(out + (size_t)n * 128 + 8 * sl) = r;
  }
}

// ---------------- layer-2 aggregation FUSED with classifier (news rows only) ----------------
__global__ void gat_agg_cls_kernel(const unsigned short* __restrict__ h, const float* __restrict__ a_src,
                                   const float* __restrict__ a_dst, const int* __restrict__ row_ptr,
                                   const int* __restrict__ col_idx, const float* __restrict__ bias,
                                   int n_news,
                                   const float* __restrict__ Wc1, const float* __restrict__ bc1,
                                   const float* __restrict__ Wc2, const float* __restrict__ bc2,
                                   float* __restrict__ out)
{
  int n = (blockIdx.x * blockDim.x + threadIdx.x) >> 6;
  int lane = threadIdx.x & 63;
  if (n >= n_news) return;
  const int sub = lane >> 4;
  const int sl = lane & 15;
  const int head = sl >> 2;
  const int beg = row_ptr[n], end = row_ptr[n + 1];
  const float adst = a_dst[(size_t)n * 4 + head];

  float slf = a_src[(size_t)n * 4 + head] + adst;
  slf = fmaxf(slf, 0.2f * slf);
  float ps = (sub == 0) ? __expf(slf) : 0.f;
  float denom = ps;
  float acc[8];
  {
    const u16x8 hs = *(const u16x8*)(h + (size_t)n * 128 + 8 * sl);
#pragma unroll
    for (int j = 0; j < 8; ++j) acc[j] = ps * b2f(hs[j]);
  }

  int e = beg + sub;
  for (; e + 4 < end; e += 8) {
    const int s0 = col_idx[e];
    const int s1 = col_idx[e + 4];
    const u16x8 h0 = *(const u16x8*)(h + (size_t)s0 * 128 + 8 * sl);
    const u16x8 h1 = *(const u16x8*)(h + (size_t)s1 * 128 + 8 * sl);
    float l0 = a_src[(size_t)s0 * 4 + head] + adst;
    float l1 = a_src[(size_t)s1 * 4 + head] + adst;
    l0 = fmaxf(l0, 0.2f * l0);
    l1 = fmaxf(l1, 0.2f * l1);
    const float p0 = __expf(l0);
    const float p1 = __expf(l1);
    denom += p0 + p1;
#pragma unroll
    for (int j = 0; j < 8; ++j) {
      acc[j] = fmaf(p0, b2f(h0[j]), acc[j]);
      acc[j] = fmaf(p1, b2f(h1[j]), acc[j]);
    }
  }
  if (e < end) {
    const int s = col_idx[e];
    const u16x8 hv = *(const u16x8*)(h + (size_t)s * 128 + 8 * sl);
    float lg = a_src[(size_t)s * 4 + head] + adst;
    lg = fmaxf(lg, 0.2f * lg);
    const float p = __expf(lg);
    denom += p;
#pragma unroll
    for (int j = 0; j < 8; ++j) acc[j] = fmaf(p, b2f(hv[j]), acc[j]);
  }

#pragma unroll
  for (int j = 0; j < 8; ++j) {
    acc[j] += __shfl_xor(acc[j], 16);
    acc[j] += __shfl_xor(acc[j], 32);
  }
  denom += __shfl_xor(denom, 16);
  denom += __shfl_xor(denom, 32);

  // full fp32 node row on every lane (lane sl holds dims 8*sl..8*sl+7)
  const float inv = 1.0f / (denom + 1e-16f);
  const float4 b0 = *(const float4*)(bias + 8 * sl);
  const float4 b1 = *(const float4*)(bias + 8 * sl + 4);
  float o[8];
  o[0] = acc[0] * inv + b0.x; o[1] = acc[1] * inv + b0.y;
  o[2] = acc[2] * inv + b0.z; o[3] = acc[3] * inv + b0.w;
  o[4] = acc[4] * inv + b1.x; o[5] = acc[5] * inv + b1.y;
  o[6] = acc[6] * inv + b1.z; o[7] = acc[7] * inv + b1.w;
#pragma unroll
  for (int j = 0; j < 8; ++j)
    o[j] = (o[j] > 0.f) ? o[j] : expm1f(o[j]);    // ELU

  // classifier: lane owns column `lane` of the 64-wide hidden layer
  float c = 0.f;
#pragma unroll
  for (int j = 0; j < 8; ++j) {
#pragma unroll
    for (int kb = 0; kb < 16; ++kb) {
      float x = __shfl(o[j], kb);                 // dim = kb*8 + j (from lane kb, sub 0)
      c = fmaf(x, Wc1[(kb * 8 + j) * 64 + lane], c);
    }
  }
  c += bc1[lane];
  c = fmaxf(c, 0.f);
  float o0 = c * Wc2[lane * 2 + 0];
  float o1 = c * Wc2[lane * 2 + 1];
#pragma unroll
  for (int off = 1; off < 64; off <<= 1) {
    o0 += __shfl_xor(o0, off);
    o1 += __shfl_xor(o1, off);
  }
  if (lane == 0) {
    out[(size_t)n * 2 + 0] = o0 + bc2[0];
    out[(size_t)n * 2 + 1] = o1 + bc2[1];
  }
}

extern "C" void kernel_launch(void* const* d_in, const int* in_sizes, int n_in,
                              void* d_out, int out_size, void* d_ws, size_t ws_size,
                              hipStream_t stream)
{
  const float* x_news = (const float*)d_in[0];
  const float* x_tw   = (const float*)d_in[1];
  const int*   ei     = (const int*)d_in[2];
  const float* W_news = (const float*)d_in[3];
  const float* b_news = (const float*)d_in[4];
  const float* W_tw   = (const float*)d_in[5];
  const float* b_tw   = (const float*)d_in[6];
  const float* g1W  = (const float*)d_in[7];
  const float* g1as = (const float*)d_in[8];
  const float* g1ad = (const float*)d_in[9];
  const float* g1b  = (const float*)d_in[10];
  const float* g2W  = (const float*)d_in[11];
  const float* g2as = (const float*)d_in[12];
  const float* g2ad = (const float*)d_in[13];
  const float* g2b  = (const float*)d_in[14];
  const float* Wc1  = (const float*)d_in[15];
  const float* bc1  = (const float*)d_in[16];
  const float* Wc2  = (const float*)d_in[17];
  const float* bc2  = (const float*)d_in[18];

  const int n_news = in_sizes[0] / 768;
  const int n_tw   = in_sizes[1] / 512;
  const int N = n_news + n_tw;
  const int E = in_sizes[2] / 2;
  const int* src = ei;
  const int* dst = ei + E;
  const int nb = (N + 255) >> 8;      // buckets of 256 nodes

  char* ws = (char*)d_ws;
  size_t off = 0;
  auto alloc = [&](size_t bytes) -> void* {
    void* p = ws + off;
    off += (bytes + 255) & ~(size_t)255;
    return p;
  };
  unsigned short* x_feat = (unsigned short*)alloc((size_t)N * 128 * 2);
  unsigned short* h_feat = (unsigned short*)alloc((size_t)N * 128 * 2);
  float* a_src   = (float*)alloc((size_t)N * 4 * 4);
  float* a_dst   = (float*)alloc((size_t)N * 4 * 4);
  int*   row_ptr = (int*)alloc((size_t)(N + 1) * 4);
  int*   col_idx = (int*)alloc((size_t)E * 4);
  int2*  pairs   = (int2*)alloc((size_t)E * 8);
  int*   bcount  = (int*)alloc(2048);
  int*   bstart  = (int*)alloc(2052);
  int*   bcur    = (int*)alloc(2048);
  unsigned short* WT_news = (unsigned short*)alloc((size_t)128 * 768 * 2);
  unsigned short* WT_tw   = (unsigned short*)alloc((size_t)128 * 512 * 2);
  unsigned short* WT_g1   = (unsigned short*)alloc((size_t)128 * 128 * 2);
  unsigned short* WT_g2   = (unsigned short*)alloc((size_t)128 * 128 * 2);

  hipMemsetAsync(bcount, 0, 2048, stream);

  // one-off weight transposes (fp32 -> bf16, [K][128] -> [128][K]) — single launch
  transpose_all_kernel<<<768, 256, 0, stream>>>(W_news, WT_news, W_tw, WT_tw, g1W, WT_g1, g2W, WT_g2);

  // mega1: tweets GEMM | news GEMM | bucket histogram (all independent)
  const int nb_tw = (n_tw + 63) / 64;
  const int nb_news = (n_news + 31) / 32;
  const int nb_hist = (E + 8191) / 8192;
  mega1_kernel<<<nb_tw + nb_news + nb_hist, 256, 0, stream>>>(
      nb_tw, nb_news,
      x_tw, n_tw, WT_tw, b_tw, x_feat + (size_t)n_news * 128,
      x_news, n_news, WT_news, b_news, x_feat,
      dst, E, bcount, nb);

  // bucket scan (tiny)
  bucket_scan_kernel<<<1, 512, 0, stream>>>(bcount, nb, E, bstart, bcur, row_ptr, N);

  // mega3: GAT1 GEMM+logits | bucket scatter (both ready after scan)
  const int nb_g = (N + 63) / 64;
  mega3_kernel<<<nb_g + nb_hist, 256, 0, stream>>>(
      nb_g, x_feat, N, WT_g1, h_feat, g1as, g1ad, a_src, a_dst,
      src, dst, E, bcur, pairs);

  // per-bucket CSR finalize
  bucket_csr_kernel<<<nb, 256, 0, stream>>>(pairs, bstart, N, row_ptr, col_idx);

  // GAT layer 1 aggregation (full N: outputs feed layer-2 GEMM as gathered srcs)
  gat_aggregate_kernel<<<(N + 3) / 4, 256, 0, stream>>>(h_feat, a_src, a_dst, row_ptr, col_idx, g1b, N, x_feat);

  // GAT layer 2: GEMM (full N) + aggregation fused with classifier (news rows only)
  gemm_kernel<64, 128, 0, 1, unsigned short><<<nb_g, 256, 0, stream>>>(
      x_feat, N, WT_g2, nullptr, h_feat, g2as, g2ad, a_src, a_dst);
  gat_agg_cls_kernel<<<(n_news + 3) / 4, 256, 0, stream>>>(
      h_feat, a_src, a_dst, row_ptr, col_idx, g2b, n_news,
      Wc1, bc1, Wc2, bc2, (float*)d_out);
}